// Round 2
// baseline (1333.603 us; speedup 1.0000x reference)
//
#include <hip/hip_runtime.h>
#include <hip/hip_bf16.h>
#include <cstdint>
#include <cstddef>

typedef __bf16 bf16x8 __attribute__((ext_vector_type(8)));
typedef float  f32x4  __attribute__((ext_vector_type(4)));

static constexpr int TOK  = 4096;            // B*S
static constexpr int H    = 2048;
static constexpr int E    = 8;
static constexpr int IDIM = 1024;
static constexpr int ISD  = 4096;
static constexpr int NCOL = ISD + E * IDIM;  // 12288

// async global->LDS, 16B/lane; LDS dest = wave-uniform base + lane*16
__device__ __forceinline__ void gll16(const void* g, void* l) {
  __builtin_amdgcn_global_load_lds((const __attribute__((address_space(1))) void*)g,
                                   (__attribute__((address_space(3))) void*)l, 16, 0, 0);
}

__device__ __forceinline__ unsigned short f2bf(float f) {  // RNE fp32->bf16
  unsigned int u = __float_as_uint(f);
  u = (u + 0x7fffu + ((u >> 16) & 1u)) >> 16;
  return (unsigned short)u;
}

// ---- dtype detection: low 16 bits of uint32 look like plausible bf16? ----
__global__ __launch_bounds__(256) void detect_kernel(const unsigned int* __restrict__ x,
                                                     int* __restrict__ flag) {
  __shared__ int sh[256];
  const int tid = threadIdx.x;
  int c = 0;
  for (int i = tid; i < 1024; i += 256) {
    const unsigned int e = (x[i] >> 7) & 0xFFu;  // exp field of low half as bf16
    c += (e >= 100u && e <= 150u) ? 1 : 0;
  }
  sh[tid] = c;
  __syncthreads();
  if (tid == 0) {
    int s = 0;
    for (int i = 0; i < 256; ++i) s += sh[i];
    *flag = (s > 512) ? 1 : 0;   // 1 => inputs are bf16; 0 => fp32
  }
}

// ---- fp32 -> bf16 conversion (no-op when inputs already bf16) ----
__global__ __launch_bounds__(256) void convert_kernel(const float* __restrict__ src,
                                                      unsigned short* __restrict__ dst,
                                                      int n4, const int* __restrict__ flag) {
  if (*flag) return;
  int i = blockIdx.x * 256 + threadIdx.x;
  const int stride = gridDim.x * 256;
  for (; i < n4; i += stride) {
    const float4 v = ((const float4*)src)[i];
    ushort4 o;
    o.x = f2bf(v.x); o.y = f2bf(v.y); o.z = f2bf(v.z); o.w = f2bf(v.w);
    ((ushort4*)dst)[i] = o;
  }
}

// ---- router: fp32 logits from ORIGINAL-precision inputs, top-2, sigmoid ----
__global__ __launch_bounds__(256) void router_kernel(
    const void* __restrict__ x_, const void* __restrict__ rw_,
    void* __restrict__ out, float* __restrict__ scale, const int* __restrict__ flagp)
{
  const int bfmode = *flagp;
  const int t   = blockIdx.x;
  const int tid = threadIdx.x;
  const int l   = tid & 63, w = tid >> 6;
  const int off = tid * 8;

  float xs[8];
  if (bfmode) {
    bf16x8 v = *(const bf16x8*)((const unsigned short*)x_ + (size_t)t * H + off);
#pragma unroll
    for (int j = 0; j < 8; ++j) xs[j] = (float)v[j];
  } else {
    const float* xr = (const float*)x_ + (size_t)t * H + off;
    const float4 a = *(const float4*)xr;
    const float4 b = *(const float4*)(xr + 4);
    xs[0]=a.x; xs[1]=a.y; xs[2]=a.z; xs[3]=a.w; xs[4]=b.x; xs[5]=b.y; xs[6]=b.z; xs[7]=b.w;
  }

  float p[E];
#pragma unroll
  for (int e = 0; e < E; ++e) {
    float wv[8];
    if (bfmode) {
      bf16x8 v = *(const bf16x8*)((const unsigned short*)rw_ + (size_t)e * H + off);
#pragma unroll
      for (int j = 0; j < 8; ++j) wv[j] = (float)v[j];
    } else {
      const float* wr = (const float*)rw_ + (size_t)e * H + off;
      const float4 a = *(const float4*)wr;
      const float4 b = *(const float4*)(wr + 4);
      wv[0]=a.x; wv[1]=a.y; wv[2]=a.z; wv[3]=a.w; wv[4]=b.x; wv[5]=b.y; wv[6]=b.z; wv[7]=b.w;
    }
    float s = 0.f;
#pragma unroll
    for (int j = 0; j < 8; ++j) s = fmaf(xs[j], wv[j], s);
    p[e] = s;
  }
#pragma unroll
  for (int e = 0; e < E; ++e)
    for (int o = 32; o > 0; o >>= 1) p[e] += __shfl_down(p[e], o);

  __shared__ float red[E][4];
  __shared__ float lg[E];
  __shared__ float sres[2];
  __shared__ int   ires[2];
  if (l == 0) {
#pragma unroll
    for (int e = 0; e < E; ++e) red[e][w] = p[e];
  }
  __syncthreads();
  if (tid < E) {
    const float v = red[tid][0] + red[tid][1] + red[tid][2] + red[tid][3];
    lg[tid] = v;
    const size_t oi = (size_t)TOK * H + (size_t)t * E + tid;
    if (bfmode) ((unsigned short*)out)[oi] = f2bf(v);
    else        ((float*)out)[oi] = v;
  }
  __syncthreads();
  if (tid == 0) {
    int i0 = 0; float v0 = lg[0];
    for (int e = 1; e < E; ++e) if (lg[e] > v0) { v0 = lg[e]; i0 = e; }
    int i1 = -1; float v1 = 0.f; bool init = false;
    for (int e = 0; e < E; ++e) {
      if (e == i0) continue;
      if (!init || lg[e] > v1) { v1 = lg[e]; i1 = e; init = true; }
    }
    sres[0] = 1.f / (1.f + expf(-v0)); ires[0] = i0;
    sres[1] = 1.f / (1.f + expf(-v1)); ires[1] = i1;
  }
  __syncthreads();
  if (tid < E) {
    float s = 0.f;
    if (tid == ires[0]) s = sres[0];
    else if (tid == ires[1]) s = sres[1];
    scale[(size_t)t * E + tid] = s;
  }
}

// ---- fused gate+up GEMM: hmid = silu(s*g)*(s*u), shared + 8 experts ----
__global__ __launch_bounds__(256) void gateup_kernel(
    const void* __restrict__ xo_,  const unsigned short* __restrict__ cx,
    const void* __restrict__ gwo_, const unsigned short* __restrict__ cgw,
    const void* __restrict__ uwo_, const unsigned short* __restrict__ cuw,
    const void* __restrict__ sgo_, const unsigned short* __restrict__ csgw,
    const void* __restrict__ suo_, const unsigned short* __restrict__ csuw,
    const float* __restrict__ scale,
    unsigned short* __restrict__ hmid, const int* __restrict__ flagp)
{
  const int bfmode = *flagp;
  const unsigned short* x      = bfmode ? (const unsigned short*)xo_  : cx;
  const unsigned short* gate_w = bfmode ? (const unsigned short*)gwo_ : cgw;
  const unsigned short* up_w   = bfmode ? (const unsigned short*)uwo_ : cuw;
  const unsigned short* sgate_w= bfmode ? (const unsigned short*)sgo_ : csgw;
  const unsigned short* sup_w  = bfmode ? (const unsigned short*)suo_ : csuw;

  __shared__ __attribute__((aligned(16))) unsigned short As[128 * 64];
  __shared__ __attribute__((aligned(16))) unsigned short Bgs[64 * 64];
  __shared__ __attribute__((aligned(16))) unsigned short Bus[64 * 64];

  const int tid = threadIdx.x;
  const int l = tid & 63, w = tid >> 6;
  const int m0 = blockIdx.y * 128;
  const int jb = blockIdx.x * 64;

  const unsigned short *gB, *uB;
  const bool is_shared = (jb < ISD);
  int e = 0;
  if (is_shared) {
    gB = sgate_w + (size_t)jb * H;
    uB = sup_w   + (size_t)jb * H;
  } else {
    const int jj = jb - ISD;
    e  = jj >> 10;
    gB = gate_w + (size_t)jj * H;
    uB = up_w   + (size_t)jj * H;
  }

  f32x4 accg[4][2] = {};
  f32x4 accu[4][2] = {};
  const int wm = (w >> 1) * 64;
  const int wn = (w & 1) * 32;

  for (int k0 = 0; k0 < H; k0 += 64) {
#pragma unroll
    for (int j = 0; j < 4; ++j) {
      const int g = j * 256 + tid;
      const int r = g >> 3, c = g & 7;
      gll16(x + (size_t)(m0 + r) * H + k0 + c * 8, &As[g * 8]);
    }
#pragma unroll
    for (int j = 0; j < 2; ++j) {
      const int g = j * 256 + tid;
      const int r = g >> 3, c = g & 7;
      gll16(gB + (size_t)r * H + k0 + c * 8, &Bgs[g * 8]);
      gll16(uB + (size_t)r * H + k0 + c * 8, &Bus[g * 8]);
    }
    __syncthreads();
#pragma unroll
    for (int ks = 0; ks < 64; ks += 32) {
      const int koff = ks + (l >> 4) * 8;
      bf16x8 a[4], bg[2], bu[2];
#pragma unroll
      for (int mt = 0; mt < 4; ++mt)
        a[mt] = *(const bf16x8*)&As[(wm + mt * 16 + (l & 15)) * 64 + koff];
#pragma unroll
      for (int nt = 0; nt < 2; ++nt) {
        bg[nt] = *(const bf16x8*)&Bgs[(wn + nt * 16 + (l & 15)) * 64 + koff];
        bu[nt] = *(const bf16x8*)&Bus[(wn + nt * 16 + (l & 15)) * 64 + koff];
      }
#pragma unroll
      for (int mt = 0; mt < 4; ++mt)
#pragma unroll
        for (int nt = 0; nt < 2; ++nt) {
          accg[mt][nt] = __builtin_amdgcn_mfma_f32_16x16x32_bf16(a[mt], bg[nt], accg[mt][nt], 0, 0, 0);
          accu[mt][nt] = __builtin_amdgcn_mfma_f32_16x16x32_bf16(a[mt], bu[nt], accu[mt][nt], 0, 0, 0);
        }
    }
    __syncthreads();
  }

  const int quad = l >> 4;
#pragma unroll
  for (int mt = 0; mt < 4; ++mt) {
#pragma unroll
    for (int r = 0; r < 4; ++r) {
      const int t = m0 + wm + mt * 16 + quad * 4 + r;
      const float s = is_shared ? 1.0f : scale[(size_t)t * E + e];
#pragma unroll
      for (int nt = 0; nt < 2; ++nt) {
        const int j = jb + wn + nt * 16 + (l & 15);
        const float g = accg[mt][nt][r] * s;
        const float u = accu[mt][nt][r] * s;
        const float hm = (g / (1.f + expf(-g))) * u;
        hmid[(size_t)t * NCOL + j] = f2bf(hm);
      }
    }
  }
}

// ---- down GEMM: out = hmid[T,12288] . Bcat[2048,12288]^T ----
__global__ __launch_bounds__(256) void down_kernel(
    const unsigned short* __restrict__ hmid,
    const void* __restrict__ dwo_,  const unsigned short* __restrict__ cdw,
    const void* __restrict__ sdwo_, const unsigned short* __restrict__ csdw,
    void* __restrict__ out, const int* __restrict__ flagp)
{
  const int bfmode = *flagp;
  const unsigned short* down_w  = bfmode ? (const unsigned short*)dwo_  : cdw;
  const unsigned short* sdown_w = bfmode ? (const unsigned short*)sdwo_ : csdw;

  __shared__ __attribute__((aligned(16))) unsigned short As[128 * 64];
  __shared__ __attribute__((aligned(16))) unsigned short Bs[128 * 64];

  const int tid = threadIdx.x;
  const int l = tid & 63, w = tid >> 6;
  const int m0 = blockIdx.y * 128;
  const int n0 = blockIdx.x * 128;

  f32x4 acc[4][4] = {};
  const int wm = (w >> 1) * 64;
  const int wn = (w & 1) * 64;

  for (int k0 = 0; k0 < NCOL; k0 += 64) {
    const unsigned short* Bbase;
    size_t ldb;
    if (k0 < ISD) { Bbase = sdown_w + k0; ldb = ISD; }
    else {
      const int kk = k0 - ISD;
      const int ex = kk >> 10;
      Bbase = down_w + (size_t)ex * H * IDIM + (kk & 1023);
      ldb = IDIM;
    }
#pragma unroll
    for (int j = 0; j < 4; ++j) {
      const int g = j * 256 + tid;
      const int r = g >> 3, c = g & 7;
      gll16(hmid + (size_t)(m0 + r) * NCOL + k0 + c * 8, &As[g * 8]);
    }
#pragma unroll
    for (int j = 0; j < 4; ++j) {
      const int g = j * 256 + tid;
      const int r = g >> 3, c = g & 7;
      gll16(Bbase + (size_t)(n0 + r) * ldb + c * 8, &Bs[g * 8]);
    }
    __syncthreads();
#pragma unroll
    for (int ks = 0; ks < 64; ks += 32) {
      const int koff = ks + (l >> 4) * 8;
      bf16x8 a[4], b[4];
#pragma unroll
      for (int mt = 0; mt < 4; ++mt)
        a[mt] = *(const bf16x8*)&As[(wm + mt * 16 + (l & 15)) * 64 + koff];
#pragma unroll
      for (int nt = 0; nt < 4; ++nt)
        b[nt] = *(const bf16x8*)&Bs[(wn + nt * 16 + (l & 15)) * 64 + koff];
#pragma unroll
      for (int mt = 0; mt < 4; ++mt)
#pragma unroll
        for (int nt = 0; nt < 4; ++nt)
          acc[mt][nt] = __builtin_amdgcn_mfma_f32_16x16x32_bf16(a[mt], b[nt], acc[mt][nt], 0, 0, 0);
    }
    __syncthreads();
  }

  const int quad = l >> 4;
  if (bfmode) {
    unsigned short* o = (unsigned short*)out;
#pragma unroll
    for (int mt = 0; mt < 4; ++mt)
#pragma unroll
      for (int nt = 0; nt < 4; ++nt)
#pragma unroll
        for (int r = 0; r < 4; ++r) {
          const int t = m0 + wm + mt * 16 + quad * 4 + r;
          const int n = n0 + wn + nt * 16 + (l & 15);
          o[(size_t)t * H + n] = f2bf(acc[mt][nt][r]);
        }
  } else {
    float* o = (float*)out;
#pragma unroll
    for (int mt = 0; mt < 4; ++mt)
#pragma unroll
      for (int nt = 0; nt < 4; ++nt)
#pragma unroll
        for (int r = 0; r < 4; ++r) {
          const int t = m0 + wm + mt * 16 + quad * 4 + r;
          const int n = n0 + wn + nt * 16 + (l & 15);
          o[(size_t)t * H + n] = acc[mt][nt][r];
        }
  }
}

extern "C" void kernel_launch(void* const* d_in, const int* in_sizes, int n_in,
                              void* d_out, int out_size, void* d_ws, size_t ws_size,
                              hipStream_t stream) {
  const void* x   = d_in[0];
  const void* rw  = d_in[1];
  const void* gw  = d_in[2];
  const void* uw  = d_in[3];
  const void* dw  = d_in[4];
  const void* sgw = d_in[5];
  const void* suw = d_in[6];
  const void* sdw = d_in[7];

  char* wsb = (char*)d_ws;
  int*   flag  = (int*)wsb;                                   // 256 B reserved
  float* scale = (float*)(wsb + 256);                         // [T,E] fp32
  unsigned short* hmid = (unsigned short*)(wsb + 256 + (size_t)TOK * E * 4);  // [T,NCOL] bf16
  unsigned short* cx   = (unsigned short*)(wsb + 256 + (size_t)TOK * E * 4 + (size_t)TOK * NCOL * 2);
  unsigned short* crw  = cx  + (size_t)TOK * H;
  unsigned short* cgw  = crw + (size_t)E * H;
  unsigned short* cuw  = cgw + (size_t)E * IDIM * H;
  unsigned short* cdw  = cuw + (size_t)E * IDIM * H;
  unsigned short* csgw = cdw + (size_t)E * H * IDIM;
  unsigned short* csuw = csgw + (size_t)ISD * H;
  unsigned short* csdw = csuw + (size_t)ISD * H;

  detect_kernel<<<1, 256, 0, stream>>>((const unsigned int*)x, flag);

  convert_kernel<<<1024, 256, 0, stream>>>((const float*)x,   cx,   (TOK * H) / 4,        flag);
  convert_kernel<<<16,   256, 0, stream>>>((const float*)rw,  crw,  (E * H) / 4,          flag);
  convert_kernel<<<1024, 256, 0, stream>>>((const float*)gw,  cgw,  (E * IDIM * H) / 4,   flag);
  convert_kernel<<<1024, 256, 0, stream>>>((const float*)uw,  cuw,  (E * IDIM * H) / 4,   flag);
  convert_kernel<<<1024, 256, 0, stream>>>((const float*)dw,  cdw,  (E * H * IDIM) / 4,   flag);
  convert_kernel<<<1024, 256, 0, stream>>>((const float*)sgw, csgw, (ISD * H) / 4,        flag);
  convert_kernel<<<1024, 256, 0, stream>>>((const float*)suw, csuw, (ISD * H) / 4,        flag);
  convert_kernel<<<1024, 256, 0, stream>>>((const float*)sdw, csdw, (ISD * H) / 4,        flag);

  router_kernel<<<TOK, 256, 0, stream>>>(x, rw, d_out, scale, flag);

  dim3 g1(NCOL / 64, TOK / 128);  // 192 x 32
  gateup_kernel<<<g1, 256, 0, stream>>>(x, cx, gw, cgw, uw, cuw, sgw, csgw, suw, csuw,
                                        scale, hmid, flag);

  dim3 g2(H / 128, TOK / 128);    // 16 x 32
  down_kernel<<<g2, 256, 0, stream>>>(hmid, dw, cdw, sdw, csdw, d_out, flag);
}

// Round 3
// 1165.698 us; speedup vs baseline: 1.1440x; 1.1440x over previous
//
#include <hip/hip_runtime.h>
#include <hip/hip_bf16.h>
#include <cstdint>
#include <cstddef>

typedef __bf16 bf16x8 __attribute__((ext_vector_type(8)));
typedef float  f32x4  __attribute__((ext_vector_type(4)));

static constexpr int TOK  = 4096;            // B*S
static constexpr int H    = 2048;
static constexpr int E    = 8;
static constexpr int IDIM = 1024;
static constexpr int ISD  = 4096;
static constexpr int NCOL = ISD + E * IDIM;  // 12288

// async global->LDS, 16B/lane; LDS dest = wave-uniform base + lane*16
__device__ __forceinline__ void gll16(const void* g, void* l) {
  __builtin_amdgcn_global_load_lds((const __attribute__((address_space(1))) void*)g,
                                   (__attribute__((address_space(3))) void*)l, 16, 0, 0);
}

__device__ __forceinline__ unsigned short f2bf(float f) {  // RNE fp32->bf16
  unsigned int u = __float_as_uint(f);
  u = (u + 0x7fffu + ((u >> 16) & 1u)) >> 16;
  return (unsigned short)u;
}

// ---- dtype detection: low 16 bits of uint32 look like plausible bf16? ----
__global__ __launch_bounds__(256) void detect_kernel(const unsigned int* __restrict__ x,
                                                     int* __restrict__ flag) {
  __shared__ int sh[256];
  const int tid = threadIdx.x;
  int c = 0;
  for (int i = tid; i < 1024; i += 256) {
    const unsigned int e = (x[i] >> 7) & 0xFFu;
    c += (e >= 100u && e <= 150u) ? 1 : 0;
  }
  sh[tid] = c;
  __syncthreads();
  if (tid == 0) {
    int s = 0;
    for (int i = 0; i < 256; ++i) s += sh[i];
    *flag = (s > 512) ? 1 : 0;   // 1 => inputs bf16; 0 => fp32
  }
}

// ---- fp32 -> bf16 conversion (no-op when inputs already bf16) ----
__global__ __launch_bounds__(256) void convert_kernel(const float* __restrict__ src,
                                                      unsigned short* __restrict__ dst,
                                                      int n4, const int* __restrict__ flag) {
  if (*flag) return;
  int i = blockIdx.x * 256 + threadIdx.x;
  const int stride = gridDim.x * 256;
  for (; i < n4; i += stride) {
    const float4 v = ((const float4*)src)[i];
    ushort4 o;
    o.x = f2bf(v.x); o.y = f2bf(v.y); o.z = f2bf(v.z); o.w = f2bf(v.w);
    ((ushort4*)dst)[i] = o;
  }
}

// ---- router: fp32 logits from ORIGINAL-precision inputs, top-2, sigmoid ----
__global__ __launch_bounds__(256) void router_kernel(
    const void* __restrict__ x_, const void* __restrict__ rw_,
    void* __restrict__ out, float* __restrict__ scale, const int* __restrict__ flagp)
{
  const int bfmode = *flagp;
  const int t   = blockIdx.x;
  const int tid = threadIdx.x;
  const int l   = tid & 63, w = tid >> 6;
  const int off = tid * 8;

  float xs[8];
  if (bfmode) {
    bf16x8 v = *(const bf16x8*)((const unsigned short*)x_ + (size_t)t * H + off);
#pragma unroll
    for (int j = 0; j < 8; ++j) xs[j] = (float)v[j];
  } else {
    const float* xr = (const float*)x_ + (size_t)t * H + off;
    const float4 a = *(const float4*)xr;
    const float4 b = *(const float4*)(xr + 4);
    xs[0]=a.x; xs[1]=a.y; xs[2]=a.z; xs[3]=a.w; xs[4]=b.x; xs[5]=b.y; xs[6]=b.z; xs[7]=b.w;
  }

  float p[E];
#pragma unroll
  for (int e = 0; e < E; ++e) {
    float wv[8];
    if (bfmode) {
      bf16x8 v = *(const bf16x8*)((const unsigned short*)rw_ + (size_t)e * H + off);
#pragma unroll
      for (int j = 0; j < 8; ++j) wv[j] = (float)v[j];
    } else {
      const float* wr = (const float*)rw_ + (size_t)e * H + off;
      const float4 a = *(const float4*)wr;
      const float4 b = *(const float4*)(wr + 4);
      wv[0]=a.x; wv[1]=a.y; wv[2]=a.z; wv[3]=a.w; wv[4]=b.x; wv[5]=b.y; wv[6]=b.z; wv[7]=b.w;
    }
    float s = 0.f;
#pragma unroll
    for (int j = 0; j < 8; ++j) s = fmaf(xs[j], wv[j], s);
    p[e] = s;
  }
#pragma unroll
  for (int e = 0; e < E; ++e)
    for (int o = 32; o > 0; o >>= 1) p[e] += __shfl_down(p[e], o);

  __shared__ float red[E][4];
  __shared__ float lg[E];
  __shared__ float sres[2];
  __shared__ int   ires[2];
  if (l == 0) {
#pragma unroll
    for (int e = 0; e < E; ++e) red[e][w] = p[e];
  }
  __syncthreads();
  if (tid < E) {
    const float v = red[tid][0] + red[tid][1] + red[tid][2] + red[tid][3];
    lg[tid] = v;
    const size_t oi = (size_t)TOK * H + (size_t)t * E + tid;
    if (bfmode) ((unsigned short*)out)[oi] = f2bf(v);
    else        ((float*)out)[oi] = v;
  }
  __syncthreads();
  if (tid == 0) {
    int i0 = 0; float v0 = lg[0];
    for (int e = 1; e < E; ++e) if (lg[e] > v0) { v0 = lg[e]; i0 = e; }
    int i1 = -1; float v1 = 0.f; bool init = false;
    for (int e = 0; e < E; ++e) {
      if (e == i0) continue;
      if (!init || lg[e] > v1) { v1 = lg[e]; i1 = e; init = true; }
    }
    sres[0] = 1.f / (1.f + expf(-v0)); ires[0] = i0;
    sres[1] = 1.f / (1.f + expf(-v1)); ires[1] = i1;
  }
  __syncthreads();
  if (tid < E) {
    float s = 0.f;
    if (tid == ires[0]) s = sres[0];
    else if (tid == ires[1]) s = sres[1];
    scale[(size_t)t * E + tid] = s;
  }
}

// ---- fused gate+up GEMM: hmid = silu(s*g)*(s*u), shared + 8 experts ----
// LDS layout XOR-swizzled: global chunk c (16B) of row r lives at LDS column c^(r&7).
// grid: x = token-tile (32, fastest -> consecutive blocks share the weight tile),
//       y = hmid-col-tile (192)
__global__ __launch_bounds__(256) void gateup_kernel(
    const void* __restrict__ xo_,  const unsigned short* __restrict__ cx,
    const void* __restrict__ gwo_, const unsigned short* __restrict__ cgw,
    const void* __restrict__ uwo_, const unsigned short* __restrict__ cuw,
    const void* __restrict__ sgo_, const unsigned short* __restrict__ csgw,
    const void* __restrict__ suo_, const unsigned short* __restrict__ csuw,
    const float* __restrict__ scale,
    unsigned short* __restrict__ hmid, const int* __restrict__ flagp)
{
  const int bfmode = *flagp;
  const unsigned short* x      = bfmode ? (const unsigned short*)xo_  : cx;
  const unsigned short* gate_w = bfmode ? (const unsigned short*)gwo_ : cgw;
  const unsigned short* up_w   = bfmode ? (const unsigned short*)uwo_ : cuw;
  const unsigned short* sgate_w= bfmode ? (const unsigned short*)sgo_ : csgw;
  const unsigned short* sup_w  = bfmode ? (const unsigned short*)suo_ : csuw;

  __shared__ __attribute__((aligned(16))) unsigned short As[128 * 64];
  __shared__ __attribute__((aligned(16))) unsigned short Bgs[64 * 64];
  __shared__ __attribute__((aligned(16))) unsigned short Bus[64 * 64];

  const int tid = threadIdx.x;
  const int l = tid & 63, w = tid >> 6;
  const int m0 = blockIdx.x * 128;
  const int jb = blockIdx.y * 64;

  const unsigned short *gB, *uB;
  const bool is_shared = (jb < ISD);
  int e = 0;
  if (is_shared) {
    gB = sgate_w + (size_t)jb * H;
    uB = sup_w   + (size_t)jb * H;
  } else {
    const int jj = jb - ISD;
    e  = jj >> 10;
    gB = gate_w + (size_t)jj * H;
    uB = up_w   + (size_t)jj * H;
  }

  f32x4 accg[4][2] = {};
  f32x4 accu[4][2] = {};
  const int wm = (w >> 1) * 64;
  const int wn = (w & 1) * 32;
  const int quad = l >> 4, lm = l & 15;

  for (int k0 = 0; k0 < H; k0 += 64) {
#pragma unroll
    for (int j = 0; j < 4; ++j) {
      const int g = j * 256 + tid;
      const int r = g >> 3, c = g & 7;
      const int cc = c ^ (r & 7);                       // swizzled source chunk
      gll16(x + (size_t)(m0 + r) * H + k0 + cc * 8, &As[g * 8]);
    }
#pragma unroll
    for (int j = 0; j < 2; ++j) {
      const int g = j * 256 + tid;
      const int r = g >> 3, c = g & 7;
      const int cc = c ^ (r & 7);
      gll16(gB + (size_t)r * H + k0 + cc * 8, &Bgs[g * 8]);
      gll16(uB + (size_t)r * H + k0 + cc * 8, &Bus[g * 8]);
    }
    __syncthreads();
#pragma unroll
    for (int ks = 0; ks < 64; ks += 32) {
      const int kc  = (ks >> 3) + quad;                 // global chunk wanted
      const int csw = (kc ^ (lm & 7)) * 8;              // swizzled LDS col (row&7 == lm&7)
      bf16x8 a[4], bg[2], bu[2];
#pragma unroll
      for (int mt = 0; mt < 4; ++mt)
        a[mt] = *(const bf16x8*)&As[(wm + mt * 16 + lm) * 64 + csw];
#pragma unroll
      for (int nt = 0; nt < 2; ++nt) {
        bg[nt] = *(const bf16x8*)&Bgs[(wn + nt * 16 + lm) * 64 + csw];
        bu[nt] = *(const bf16x8*)&Bus[(wn + nt * 16 + lm) * 64 + csw];
      }
#pragma unroll
      for (int mt = 0; mt < 4; ++mt)
#pragma unroll
        for (int nt = 0; nt < 2; ++nt) {
          accg[mt][nt] = __builtin_amdgcn_mfma_f32_16x16x32_bf16(a[mt], bg[nt], accg[mt][nt], 0, 0, 0);
          accu[mt][nt] = __builtin_amdgcn_mfma_f32_16x16x32_bf16(a[mt], bu[nt], accu[mt][nt], 0, 0, 0);
        }
    }
    __syncthreads();
  }

  #pragma unroll
  for (int mt = 0; mt < 4; ++mt) {
#pragma unroll
    for (int r = 0; r < 4; ++r) {
      const int t = m0 + wm + mt * 16 + quad * 4 + r;
      const float s = is_shared ? 1.0f : scale[(size_t)t * E + e];
#pragma unroll
      for (int nt = 0; nt < 2; ++nt) {
        const int j = jb + wn + nt * 16 + lm;
        const float g = accg[mt][nt][r] * s;
        const float u = accu[mt][nt][r] * s;
        const float hm = (g / (1.f + expf(-g))) * u;
        hmid[(size_t)t * NCOL + j] = f2bf(hm);
      }
    }
  }
}

// ---- down GEMM: out = hmid[T,12288] . Bcat[2048,12288]^T (XOR-swizzled LDS) ----
__global__ __launch_bounds__(256) void down_kernel(
    const unsigned short* __restrict__ hmid,
    const void* __restrict__ dwo_,  const unsigned short* __restrict__ cdw,
    const void* __restrict__ sdwo_, const unsigned short* __restrict__ csdw,
    void* __restrict__ out, const int* __restrict__ flagp)
{
  const int bfmode = *flagp;
  const unsigned short* down_w  = bfmode ? (const unsigned short*)dwo_  : cdw;
  const unsigned short* sdown_w = bfmode ? (const unsigned short*)sdwo_ : csdw;

  __shared__ __attribute__((aligned(16))) unsigned short As[128 * 64];
  __shared__ __attribute__((aligned(16))) unsigned short Bs[128 * 64];

  const int tid = threadIdx.x;
  const int l = tid & 63, w = tid >> 6;
  const int m0 = blockIdx.y * 128;
  const int n0 = blockIdx.x * 128;

  f32x4 acc[4][4] = {};
  const int wm = (w >> 1) * 64;
  const int wn = (w & 1) * 64;
  const int quad = l >> 4, lm = l & 15;

  for (int k0 = 0; k0 < NCOL; k0 += 64) {
    const unsigned short* Bbase;
    size_t ldb;
    if (k0 < ISD) { Bbase = sdown_w + k0; ldb = ISD; }
    else {
      const int kk = k0 - ISD;
      const int ex = kk >> 10;
      Bbase = down_w + (size_t)ex * H * IDIM + (kk & 1023);
      ldb = IDIM;
    }
#pragma unroll
    for (int j = 0; j < 4; ++j) {
      const int g = j * 256 + tid;
      const int r = g >> 3, c = g & 7;
      const int cc = c ^ (r & 7);
      gll16(hmid + (size_t)(m0 + r) * NCOL + k0 + cc * 8, &As[g * 8]);
    }
#pragma unroll
    for (int j = 0; j < 4; ++j) {
      const int g = j * 256 + tid;
      const int r = g >> 3, c = g & 7;
      const int cc = c ^ (r & 7);
      gll16(Bbase + (size_t)(n0 + r) * ldb + cc * 8, &Bs[g * 8]);
    }
    __syncthreads();
#pragma unroll
    for (int ks = 0; ks < 64; ks += 32) {
      const int kc  = (ks >> 3) + quad;
      const int csw = (kc ^ (lm & 7)) * 8;
      bf16x8 a[4], b[4];
#pragma unroll
      for (int mt = 0; mt < 4; ++mt)
        a[mt] = *(const bf16x8*)&As[(wm + mt * 16 + lm) * 64 + csw];
#pragma unroll
      for (int nt = 0; nt < 4; ++nt)
        b[nt] = *(const bf16x8*)&Bs[(wn + nt * 16 + lm) * 64 + csw];
#pragma unroll
      for (int mt = 0; mt < 4; ++mt)
#pragma unroll
        for (int nt = 0; nt < 4; ++nt)
          acc[mt][nt] = __builtin_amdgcn_mfma_f32_16x16x32_bf16(a[mt], b[nt], acc[mt][nt], 0, 0, 0);
    }
    __syncthreads();
  }

  if (bfmode) {
    unsigned short* o = (unsigned short*)out;
#pragma unroll
    for (int mt = 0; mt < 4; ++mt)
#pragma unroll
      for (int nt = 0; nt < 4; ++nt)
#pragma unroll
        for (int r = 0; r < 4; ++r) {
          const int t = m0 + wm + mt * 16 + quad * 4 + r;
          const int n = n0 + wn + nt * 16 + lm;
          o[(size_t)t * H + n] = f2bf(acc[mt][nt][r]);
        }
  } else {
    float* o = (float*)out;
#pragma unroll
    for (int mt = 0; mt < 4; ++mt)
#pragma unroll
      for (int nt = 0; nt < 4; ++nt)
#pragma unroll
        for (int r = 0; r < 4; ++r) {
          const int t = m0 + wm + mt * 16 + quad * 4 + r;
          const int n = n0 + wn + nt * 16 + lm;
          o[(size_t)t * H + n] = acc[mt][nt][r];
        }
  }
}

extern "C" void kernel_launch(void* const* d_in, const int* in_sizes, int n_in,
                              void* d_out, int out_size, void* d_ws, size_t ws_size,
                              hipStream_t stream) {
  const void* x   = d_in[0];
  const void* rw  = d_in[1];
  const void* gw  = d_in[2];
  const void* uw  = d_in[3];
  const void* dw  = d_in[4];
  const void* sgw = d_in[5];
  const void* suw = d_in[6];
  const void* sdw = d_in[7];

  char* wsb = (char*)d_ws;
  int*   flag  = (int*)wsb;                                   // 256 B reserved
  float* scale = (float*)(wsb + 256);                         // [T,E] fp32
  unsigned short* hmid = (unsigned short*)(wsb + 256 + (size_t)TOK * E * 4);  // [T,NCOL] bf16
  unsigned short* cx   = (unsigned short*)(wsb + 256 + (size_t)TOK * E * 4 + (size_t)TOK * NCOL * 2);
  unsigned short* crw  = cx  + (size_t)TOK * H;
  unsigned short* cgw  = crw + (size_t)E * H;
  unsigned short* cuw  = cgw + (size_t)E * IDIM * H;
  unsigned short* cdw  = cuw + (size_t)E * IDIM * H;
  unsigned short* csgw = cdw + (size_t)E * H * IDIM;
  unsigned short* csuw = csgw + (size_t)ISD * H;
  unsigned short* csdw = csuw + (size_t)ISD * H;

  detect_kernel<<<1, 256, 0, stream>>>((const unsigned int*)x, flag);

  convert_kernel<<<1024, 256, 0, stream>>>((const float*)x,   cx,   (TOK * H) / 4,        flag);
  convert_kernel<<<16,   256, 0, stream>>>((const float*)rw,  crw,  (E * H) / 4,          flag);
  convert_kernel<<<1024, 256, 0, stream>>>((const float*)gw,  cgw,  (E * IDIM * H) / 4,   flag);
  convert_kernel<<<1024, 256, 0, stream>>>((const float*)uw,  cuw,  (E * IDIM * H) / 4,   flag);
  convert_kernel<<<1024, 256, 0, stream>>>((const float*)dw,  cdw,  (E * H * IDIM) / 4,   flag);
  convert_kernel<<<1024, 256, 0, stream>>>((const float*)sgw, csgw, (ISD * H) / 4,        flag);
  convert_kernel<<<1024, 256, 0, stream>>>((const float*)suw, csuw, (ISD * H) / 4,        flag);
  convert_kernel<<<1024, 256, 0, stream>>>((const float*)sdw, csdw, (ISD * H) / 4,        flag);

  router_kernel<<<TOK, 256, 0, stream>>>(x, rw, d_out, scale, flag);

  dim3 g1(TOK / 128, NCOL / 64);  // 32 x 192 (x fastest: weight-tile reuse)
  gateup_kernel<<<g1, 256, 0, stream>>>(x, cx, gw, cgw, uw, cuw, sgw, csgw, suw, csuw,
                                        scale, hmid, flag);

  dim3 g2(H / 128, TOK / 128);    // 16 x 32
  down_kernel<<<g2, 256, 0, stream>>>(hmid, dw, cdw, sdw, csdw, d_out, flag);
}